// Round 7
// baseline (7257.606 us; speedup 1.0000x reference)
//
// EpisodicMemory: fp32 in/out. Persistent scan v2 (fixes R6's latency collapse).
//   prep_w  : one-shot fp32->bf16 of fc1_w, W_ih, W_hh.
//   g_kernel: per-b block gate GEMM (unchanged, ~130us).
//   persist : ONE kernel, 256 blocks x 512 threads (8 waves/CU). Block (bt,jt)
//             owns 64b x 32j. Per 8-step chunk: [stage Wih full-K in LDS; xg
//             m-iters, A-frags direct from global C (no inner barriers); stage
//             Whh full-K in LDS; 8 scan steps (h A-frags direct from global,
//             W from LDS, xg slice via small LDS stage)]. 16-block group
//             barrier per step (padded device-scope counters). h bf16 hi+lo,
//             double-buffered in global.
#include <hip/hip_runtime.h>
#include <hip/hip_bf16.h>

#define H_ 512
#define SH_ 120
#define B_ 1024
#define S_ 64

typedef __bf16 bf16x8 __attribute__((ext_vector_type(8)));
typedef float floatx4 __attribute__((ext_vector_type(4)));

__device__ __forceinline__ float bf2f(ushort u) {
    union { unsigned int i; float f; } v; v.i = ((unsigned int)u) << 16; return v.f;
}
__device__ __forceinline__ ushort f2bf(float f) {
    union { float f; unsigned int i; } v; v.f = f;
    unsigned int x = v.i;
    unsigned int r = (x + 0x7fffu + ((x >> 16) & 1u)) >> 16;  // RNE
    return (ushort)r;
}
__device__ __forceinline__ ushort f2bf_fast(float f) {       // native cvt (RNE)
    __bf16 b = (__bf16)f;
    union { __bf16 b; ushort u; } v; v.b = b; return v.u;
}

// ---------------------------------------------------------------------------
__global__ __launch_bounds__(256) void prep_w(
    const float* __restrict__ fc1w, ushort* __restrict__ fc1wb,
    const float* __restrict__ Wih,  ushort* __restrict__ Wihb,
    const float* __restrict__ Whh,  ushort* __restrict__ Whhb)
{
    const int stride = gridDim.x * blockDim.x;
    const int tid = blockIdx.x * blockDim.x + threadIdx.x;
    for (int i = tid; i < 61440; i += stride) {
        const float4 v = ((const float4*)fc1w)[i];
        ushort4 o; o.x = f2bf(v.x); o.y = f2bf(v.y); o.z = f2bf(v.z); o.w = f2bf(v.w);
        ((ushort4*)fc1wb)[i] = o;
    }
    for (int i = tid; i < 196608; i += stride) {
        const float4 v = ((const float4*)Wih)[i];
        ushort4 o; o.x = f2bf(v.x); o.y = f2bf(v.y); o.z = f2bf(v.z); o.w = f2bf(v.w);
        ((ushort4*)Wihb)[i] = o;
    }
    for (int i = tid; i < 196608; i += stride) {
        const float4 v = ((const float4*)Whh)[i];
        ushort4 o; o.x = f2bf(v.x); o.y = f2bf(v.y); o.z = f2bf(v.z); o.w = f2bf(v.w);
        ((ushort4*)Whhb)[i] = o;
    }
}

// ---------------------------------------------------------------------------
// G kernel (unchanged)
// ---------------------------------------------------------------------------
__global__ __launch_bounds__(256) void g_kernel(
    const float* __restrict__ C, const float* __restrict__ Q,
    const float* __restrict__ M, const ushort* __restrict__ fc1wb,
    const float* __restrict__ fc1b, const float* __restrict__ fc2w,
    const float* __restrict__ fc2b, float* __restrict__ G)
{
    __shared__ float qrow[H_];
    __shared__ float mrow[H_];
    __shared__ __align__(16) ushort featT[64 * 72];
    __shared__ __align__(16) ushort wT[128 * 72];
    __shared__ float h1s[64 * 132];

    const int b = blockIdx.x;
    const int t = threadIdx.x;
    for (int i = t; i < H_; i += 256) { qrow[i] = Q[(size_t)b * H_ + i]; mrow[i] = M[(size_t)b * H_ + i]; }

    const int wrow = t >> 1;
    const int wc0  = (t & 1) * 32;
    if (wrow >= SH_) {
        uint4* dst = (uint4*)&wT[wrow * 72 + wc0];
        const uint4 z = {0u, 0u, 0u, 0u};
        dst[0] = z; dst[1] = z; dst[2] = z; dst[3] = z;
    }
    __syncthreads();

    const int lane = t & 63;
    const int wv   = t >> 6;
    const int quad = lane >> 4;
    const int l15  = lane & 15;
    const int arow = wv * 16 + l15;
    const int s    = t >> 2;
    const int c0   = (t & 3) * 16;

    floatx4 acc[8];
#pragma unroll
    for (int i = 0; i < 8; ++i) acc[i] = (floatx4){0.f, 0.f, 0.f, 0.f};

    for (int hc = 0; hc < H_; hc += 64) {
        float cr[16];
        {
            const float4* csrc = (const float4*)(C + ((size_t)b * S_ + s) * H_ + hc + c0);
            *(float4*)&cr[0]  = csrc[0];
            *(float4*)&cr[4]  = csrc[1];
            *(float4*)&cr[8]  = csrc[2];
            *(float4*)&cr[12] = csrc[3];
        }
#pragma unroll
        for (int seg = 0; seg < 4; ++seg) {
#pragma unroll
            for (int u = 0; u < 16; ++u) {
                const int kk = c0 + u;
                const float c = cr[u];
                const float o = (seg == 0 || seg == 2) ? qrow[hc + kk] : mrow[hc + kk];
                const float v = (seg < 2) ? c * o : fabsf(c - o);
                featT[s * 72 + kk] = f2bf(v);
            }
            if (wrow < SH_) {
                const uint4* src = (const uint4*)(fc1wb + (size_t)wrow * (4 * H_) + seg * H_ + hc + wc0);
                uint4* dst = (uint4*)&wT[wrow * 72 + wc0];
                dst[0] = src[0]; dst[1] = src[1]; dst[2] = src[2]; dst[3] = src[3];
            }
            __syncthreads();
#pragma unroll
            for (int ks = 0; ks < 64; ks += 32) {
                const int ao = ks + quad * 8;
                const bf16x8 af = *(const bf16x8*)&featT[arow * 72 + ao];
#pragma unroll
                for (int nt = 0; nt < 8; ++nt) {
                    const bf16x8 bfr = *(const bf16x8*)&wT[(nt * 16 + l15) * 72 + ao];
                    acc[nt] = __builtin_amdgcn_mfma_f32_16x16x32_bf16(af, bfr, acc[nt], 0, 0, 0);
                }
            }
            __syncthreads();
        }
    }

#pragma unroll
    for (int nt = 0; nt < 8; ++nt) {
        const int col = nt * 16 + l15;
        const float bias = (col < SH_) ? fc1b[col] : 0.f;
#pragma unroll
        for (int r = 0; r < 4; ++r) {
            const int row = wv * 16 + quad * 4 + r;
            h1s[row * 132 + col] = (col < SH_) ? tanhf(acc[nt][r] + bias) : 0.f;
        }
    }
    __syncthreads();
    {
        const int part = t & 3;
        float sum = 0.f;
        for (int k = part; k < SH_; k += 4) sum += h1s[s * 132 + k] * fc2w[k];
        sum += __shfl_xor(sum, 1);
        sum += __shfl_xor(sum, 2);
        if (part == 0) {
            const float logit = sum + fc2b[0];
            G[(size_t)b * S_ + s] = 1.f / (1.f + expf(-logit));
        }
    }
}

// ---------------------------------------------------------------------------
// persist: dynamic LDS (ushorts): WL[8*96*72 = 55296] | xgs[6144] -> 122,880 B.
// ---------------------------------------------------------------------------
__global__ __launch_bounds__(512, 2) void persist(
    const float* __restrict__ C, const ushort* __restrict__ Wihb,
    const ushort* __restrict__ Whhb, const float* __restrict__ bih,
    const float* __restrict__ bhh, const float* __restrict__ G,
    ushort* __restrict__ xgw,
    ushort* __restrict__ hhi0, ushort* __restrict__ hlo0,
    ushort* __restrict__ hhi1, ushort* __restrict__ hlo1,
    unsigned* __restrict__ ctr, float* __restrict__ out)
{
    extern __shared__ __align__(16) ushort smem[];
    ushort* WL  = smem;          // [kci*6912 + row*72 + kk], row = gate*32 + jj
    ushort* xgs = smem + 55296;  // [bl*96 + gate*32 + jc]

    const int bx = blockIdx.x;
    const int bt = (bx & 7) * 2 + (bx >> 7);   // group's 16 blocks share one XCD
    const int jt = (bx & 127) >> 3;
    const int jb = jt * 32;
    const int bb = bt * 64;
    const int t  = threadIdx.x;
    const int lane = t & 63;
    const int wv   = t >> 6;      // 0..7
    const int quad = lane >> 4;
    const int l15  = lane & 15;
    const int mf   = wv & 3;      // scan: M-frag
    const int nh   = wv >> 2;     // scan: j-half
    ushort* __restrict__ xgp = xgw + (size_t)bx * 49152;

    for (int c = 0; c < 8; ++c) {
        // ========== stage WL = Wih slice (full K) ==========
#pragma unroll
        for (int i = 0; i < 12; ++i) {
            const int gid = i * 512 + t;
            const int row = gid >> 6, grp = gid & 63;
            const int kci = grp >> 3, kk = (grp & 7) * 8;
            const int gate = row >> 5, jj = row & 31;
            *(uint4*)&WL[kci * 6912 + row * 72 + kk] =
                *(const uint4*)(Wihb + (size_t)(gate * H_ + jb + jj) * H_ + grp * 8);
        }
        __syncthreads();

        // ========== xg phase: M-split across 8 waves, A direct from global ==========
        for (int miter = 0; miter < 4; ++miter) {
            floatx4 xa[6];
#pragma unroll
            for (int f = 0; f < 6; ++f) xa[f] = (floatx4){0.f, 0.f, 0.f, 0.f};
            const int gm = miter * 128 + wv * 16 + l15;
            const float* ap = C + ((size_t)(bb + (gm >> 3)) * S_ + c * 8 + (gm & 7)) * H_ + quad * 8;
#pragma unroll
            for (int kci = 0; kci < 8; ++kci) {
#pragma unroll
                for (int ks2 = 0; ks2 < 2; ++ks2) {
                    float cr[8];
                    *(float4*)&cr[0] = *(const float4*)(ap + kci * 64 + ks2 * 32);
                    *(float4*)&cr[4] = *(const float4*)(ap + kci * 64 + ks2 * 32 + 4);
                    __align__(16) ushort au[8];
#pragma unroll
                    for (int u = 0; u < 8; ++u) au[u] = f2bf_fast(cr[u]);
                    const bf16x8 af = *(const bf16x8*)au;
                    const int ao = ks2 * 32 + quad * 8;
#pragma unroll
                    for (int f = 0; f < 6; ++f) {
                        const bf16x8 bw = *(const bf16x8*)&WL[kci * 6912 + (f * 16 + l15) * 72 + ao];
                        xa[f] = __builtin_amdgcn_mfma_f32_16x16x32_bf16(af, bw, xa[f], 0, 0, 0);
                    }
                }
            }
#pragma unroll
            for (int f = 0; f < 6; ++f)
#pragma unroll
                for (int r = 0; r < 4; ++r) {
                    const int gr = miter * 128 + wv * 16 + quad * 4 + r;
                    xgp[(size_t)gr * 96 + f * 16 + l15] = f2bf(xa[f][r]);
                }
        }
        __syncthreads();

        // ========== stage WL = Whh slice (full K) ==========
#pragma unroll
        for (int i = 0; i < 12; ++i) {
            const int gid = i * 512 + t;
            const int row = gid >> 6, grp = gid & 63;
            const int kci = grp >> 3, kk = (grp & 7) * 8;
            const int gate = row >> 5, jj = row & 31;
            *(uint4*)&WL[kci * 6912 + row * 72 + kk] =
                *(const uint4*)(Whhb + (size_t)(gate * H_ + jb + jj) * H_ + grp * 8);
        }
        __syncthreads();

        // ========== 8 scan steps ==========
        for (int sl = 0; sl < 8; ++sl) {
            const int tstep = c * 8 + sl;
            const ushort* __restrict__ hhi_r = (tstep & 1) ? hhi1 : hhi0;
            const ushort* __restrict__ hlo_r = (tstep & 1) ? hlo1 : hlo0;
            ushort* __restrict__ hhi_w = (tstep & 1) ? hhi0 : hhi1;
            ushort* __restrict__ hlo_w = (tstep & 1) ? hlo0 : hlo1;

            // stage xg slice for this sl (reads own block's xgp; post-xg sync done)
#pragma unroll
            for (int i = 0; i < 2; ++i) {
                const int gid = i * 512 + t;
                if (gid < 768) {
                    const int row = gid / 12;
                    const int q   = gid - row * 12;
                    *(uint4*)&xgs[row * 96 + q * 8] =
                        *(const uint4*)(xgp + (size_t)(row * 8 + sl) * 96 + q * 8);
                }
            }

            floatx4 ar = (floatx4){0.f,0.f,0.f,0.f};
            floatx4 az = (floatx4){0.f,0.f,0.f,0.f};
            floatx4 an = (floatx4){0.f,0.f,0.f,0.f};
            const ushort* hhr = hhi_r + (size_t)(bb + mf * 16 + l15) * H_;
            const ushort* hlr = hlo_r + (size_t)(bb + mf * 16 + l15) * H_;
#pragma unroll
            for (int kci = 0; kci < 8; ++kci) {
#pragma unroll
                for (int ks2 = 0; ks2 < 2; ++ks2) {
                    const int k  = kci * 64 + ks2 * 32 + quad * 8;
                    const bf16x8 ahh = *(const bf16x8*)(hhr + k);
                    const bf16x8 ahl = *(const bf16x8*)(hlr + k);
                    const int ao = ks2 * 32 + quad * 8;
                    const bf16x8 wr = *(const bf16x8*)&WL[kci * 6912 + (0 * 32 + nh * 16 + l15) * 72 + ao];
                    const bf16x8 wz = *(const bf16x8*)&WL[kci * 6912 + (1 * 32 + nh * 16 + l15) * 72 + ao];
                    const bf16x8 wn = *(const bf16x8*)&WL[kci * 6912 + (2 * 32 + nh * 16 + l15) * 72 + ao];
                    ar = __builtin_amdgcn_mfma_f32_16x16x32_bf16(ahh, wr, ar, 0, 0, 0);
                    ar = __builtin_amdgcn_mfma_f32_16x16x32_bf16(ahl, wr, ar, 0, 0, 0);
                    az = __builtin_amdgcn_mfma_f32_16x16x32_bf16(ahh, wz, az, 0, 0, 0);
                    az = __builtin_amdgcn_mfma_f32_16x16x32_bf16(ahl, wz, az, 0, 0, 0);
                    an = __builtin_amdgcn_mfma_f32_16x16x32_bf16(ahh, wn, an, 0, 0, 0);
                    an = __builtin_amdgcn_mfma_f32_16x16x32_bf16(ahl, wn, an, 0, 0, 0);
                }
            }
            __syncthreads();   // xgs staged -> readable in epilogue

            // epilogue: this wave owns rows mf*16+quad*4+r, cols jb + nh*16 + l15
            {
                const int jc = nh * 16 + l15;
                const int j  = jb + jc;
                const float br  = bih[j]           + bhh[j];
                const float bz  = bih[H_ + j]      + bhh[H_ + j];
                const float bxn = bih[2 * H_ + j];
                const float bhn = bhh[2 * H_ + j];
#pragma unroll
                for (int r4 = 0; r4 < 4; ++r4) {
                    const int bl = mf * 16 + quad * 4 + r4;
                    const int b  = bb + bl;
                    const size_t idx = (size_t)b * H_ + j;
                    const float xr = bf2f(xgs[bl * 96 + jc]);
                    const float xz = bf2f(xgs[bl * 96 + 32 + jc]);
                    const float xn = bf2f(xgs[bl * 96 + 64 + jc]);
                    const float hold = bf2f(hhi_r[idx]) + bf2f(hlo_r[idx]);
                    const float g = G[(size_t)b * S_ + tstep];
                    const float rg = 1.f / (1.f + expf(-(ar[r4] + xr + br)));
                    const float zg = 1.f / (1.f + expf(-(az[r4] + xz + bz)));
                    const float ng = tanhf(xn + bxn + rg * (an[r4] + bhn));
                    const float hgru = (1.f - zg) * ng + zg * hold;
                    const float hnew = g * hgru + (1.f - g) * hold;
                    const ushort hb = f2bf(hnew);
                    hhi_w[idx] = hb;
                    hlo_w[idx] = f2bf(hnew - bf2f(hb));
                    if (tstep == S_ - 1) out[idx] = hnew;
                }
            }

            // ---- 16-block group barrier (padded counters, monotone target) ----
            __threadfence();
            __syncthreads();
            if (t == 0) {
                atomicAdd(ctr + bt * 32, 1u);
                const unsigned target = 16u * (unsigned)(tstep + 1);
                while (atomicAdd(ctr + bt * 32, 0u) < target) __builtin_amdgcn_s_sleep(2);
            }
            __syncthreads();
            __threadfence();
        }
    }
}

extern "C" void kernel_launch(void* const* d_in, const int* in_sizes, int n_in,
                              void* d_out, int out_size, void* d_ws, size_t ws_size,
                              hipStream_t stream) {
    (void)in_sizes; (void)n_in; (void)out_size; (void)ws_size;
    const float* C    = (const float*)d_in[0];
    const float* Q    = (const float*)d_in[1];
    const float* M    = (const float*)d_in[2];
    const float* fc1w = (const float*)d_in[3];
    const float* fc1b = (const float*)d_in[4];
    const float* fc2w = (const float*)d_in[5];
    const float* fc2b = (const float*)d_in[6];
    const float* Wih  = (const float*)d_in[7];
    const float* Whh  = (const float*)d_in[8];
    const float* bih  = (const float*)d_in[9];
    const float* bhh  = (const float*)d_in[10];
    float* out = (float*)d_out;

    char* ws = (char*)d_ws;
    float*    Gbuf  = (float*)ws;                          // 256 KB
    ushort*   hhi0  = (ushort*)(ws + 262144);              // 1 MB
    ushort*   hlo0  = (ushort*)(ws + 262144 + 1048576);    // 1 MB
    ushort*   hhi1  = (ushort*)(ws + 262144 + 2097152);    // 1 MB
    ushort*   hlo1  = (ushort*)(ws + 262144 + 3145728);    // 1 MB
    ushort*   fc1wb = (ushort*)(ws + 4456448);             // 480 KB
    ushort*   Wihb  = (ushort*)(ws + 4947968);             // 1.5 MB
    ushort*   Whhb  = (ushort*)(ws + 6520832);             // 1.5 MB
    ushort*   xgw   = (ushort*)(ws + 8093696);             // 24 MB (256*49152*2)
    unsigned* ctr   = (unsigned*)(ws + 8093696 + 25165824);// 2 KB (16 x 128B)

    hipMemsetAsync(hhi0, 0, 2097152, stream);              // h0 = 0 (hi+lo buf0)
    hipMemsetAsync(ctr, 0, 2048, stream);                  // barrier counters

    prep_w<<<256, 256, 0, stream>>>(fc1w, fc1wb, Wih, Wihb, Whh, Whhb);
    g_kernel<<<B_, 256, 0, stream>>>(C, Q, M, fc1wb, fc1b, fc2w, fc2b, Gbuf);

    const int lds_bytes = 122880;
    static bool attr_set = false;
    if (!attr_set) {
        hipFuncSetAttribute((const void*)persist,
                            hipFuncAttributeMaxDynamicSharedMemorySize, 160 * 1024);
        attr_set = true;
    }
    persist<<<256, 512, lds_bytes, stream>>>(C, Wihb, Whhb, bih, bhh, Gbuf,
                                             xgw, hhi0, hlo0, hhi1, hlo1, ctr, out);
}